// Round 12
// baseline (312.718 us; speedup 1.0000x reference)
//
#include <hip/hip_runtime.h>
#include <hip/hip_cooperative_groups.h>

namespace cg = cooperative_groups;

#define N_NODES 20000
#define N_EDGES 640000
#define HIDDEN  128
#define CAP     96        // max in-degree; Binomial(640K,1/20K) tail @96 ~ e^-45
#define DEG_PAD 16        // one counter per 64B line
#define NB      512       // cooperative grid: 2 blocks/CU (half the limit; R11 lesson)
#define GEMM_NB 256       // blocks 0..255 -> GEMM (1024 waves stride 1250 tiles)
#define FILL_T  ((NB - GEMM_NB) * 256)   // 65536 fill threads in phase 1
#define N_TILES (N_NODES / 16)           // 1250

typedef unsigned short bf16_t;
typedef __attribute__((ext_vector_type(8))) short short8;             // 8 bf16
typedef __attribute__((ext_vector_type(8))) unsigned short ushort8_t; // 8 u16
typedef __attribute__((ext_vector_type(4))) float floatx4;            // MFMA C/D

__device__ __forceinline__ bf16_t f2bf(float f) {
    union { float f; unsigned int i; } v; v.f = f;
    unsigned int x = v.i + 0x7FFFu + ((v.i >> 16) & 1u);   // RNE
    return (bf16_t)(x >> 16);
}
__device__ __forceinline__ float bflo(unsigned u) {
    union { unsigned i; float f; } v; v.i = u << 16; return v.f;
}
__device__ __forceinline__ float bfhi(unsigned u) {
    union { unsigned i; float f; } v; v.i = u & 0xFFFF0000u; return v.f;
}

// ---------- shared device code (used by mega + fallback kernels) -----------
__device__ __forceinline__ void do_feat_cvt(const float* feat, bf16_t* feat_bf,
                                            int start, int stride) {
    for (int i = start; i < (N_NODES * HIDDEN) / 4; i += stride) {
        float4 v = ((const float4*)feat)[i];
        ushort4 o = { f2bf(v.x), f2bf(v.y), f2bf(v.z), f2bf(v.w) };
        ((ushort4*)feat_bf)[i] = o;
    }
}
__device__ __forceinline__ void do_bp_pack(const float* Wl, const float* Wr,
                                           bf16_t* Bp, int t) {
    // Bp t = ((kt*16+nt)*64+lane)*8+j holds B[k][n]; k=kt*32+(lane>>4)*8+j,
    // n=nt*16+(lane&15); n<128 -> W_l (Y half), n>=128 -> W_r (Z half)
    if (t < 2 * HIDDEN * HIDDEN) {
        int j    = t & 7;
        int lane = (t >> 3) & 63;
        int nt   = (t >> 9) & 15;
        int kt   = t >> 13;
        int n = nt * 16 + (lane & 15);
        int k = kt * 32 + (lane >> 4) * 8 + j;
        float w = (n < HIDDEN) ? Wl[n * HIDDEN + k] : Wr[(n - HIDDEN) * HIDDEN + k];
        Bp[t] = f2bf(w);
    }
}
__device__ __forceinline__ void do_gemm_tile(int wid, int lane,
        const bf16_t* feat_bf, const bf16_t* Bp, const float* bl,
        bf16_t* Y, float* Z) {
    // A-frag: lane holds A[m=lane&15][k=kt*32+(lane>>4)*8+j]; B prepacked;
    // C/D: col=lane&15, row=(lane>>4)*4+r  [m89-verified]
    int m    = lane & 15;
    int quad = lane >> 4;
    int row0 = wid * 16;
    floatx4 acc[16];
    floatx4 zf = {0.f, 0.f, 0.f, 0.f};
#pragma unroll
    for (int nt = 0; nt < 16; ++nt) acc[nt] = zf;
    const short8* bp = (const short8*)Bp;
#pragma unroll
    for (int kt = 0; kt < 4; ++kt) {
        short8 afrag = *(const short8*)(feat_bf + (size_t)(row0 + m) * HIDDEN
                                        + kt * 32 + quad * 8);
#pragma unroll
        for (int nt = 0; nt < 16; ++nt) {
            short8 bfrag = bp[(kt * 16 + nt) * 64 + lane];
            acc[nt] = __builtin_amdgcn_mfma_f32_16x16x32_bf16(afrag, bfrag, acc[nt], 0, 0, 0);
        }
    }
    int col = lane & 15;
#pragma unroll
    for (int nt = 0; nt < 8; ++nt) {            // Y half (W_l), bf16
#pragma unroll
        for (int r = 0; r < 4; ++r) {
            int row = row0 + quad * 4 + r;
            Y[(size_t)row * HIDDEN + nt * 16 + col] = f2bf(acc[nt][r]);
        }
    }
#pragma unroll
    for (int nt = 8; nt < 16; ++nt) {           // Z half (W_r) + bias, fp32
        float b = bl[(nt - 8) * 16 + col];
#pragma unroll
        for (int r = 0; r < 4; ++r) {
            int row = row0 + quad * 4 + r;
            Z[(size_t)row * HIDDEN + (nt - 8) * 16 + col] = acc[nt][r] + b;
        }
    }
}
__device__ __forceinline__ void do_gather_node(int wid, int lane,
        const bf16_t* Y, const float* Z, const int* deg,
        const unsigned short* bucket, float* out) {
    int d_true = deg[wid * DEG_PAD];
    int d = min(d_true, CAP);
    const unsigned short* row = bucket + (size_t)wid * CAP;
    const unsigned* y = (const unsigned*)Y;
    float ax0=0,ay0=0, ax1=0,ay1=0, ax2=0,ay2=0, ax3=0,ay3=0;
    int i = 0;
    for (; i + 8 <= d; i += 8) {
        ushort8_t s = *(const ushort8_t*)(row + i);   // 8 nbrs per 16B load
        unsigned u0 = y[(int)s[0] * 64 + lane];
        unsigned u1 = y[(int)s[1] * 64 + lane];
        unsigned u2 = y[(int)s[2] * 64 + lane];
        unsigned u3 = y[(int)s[3] * 64 + lane];
        unsigned u4 = y[(int)s[4] * 64 + lane];
        unsigned u5 = y[(int)s[5] * 64 + lane];
        unsigned u6 = y[(int)s[6] * 64 + lane];
        unsigned u7 = y[(int)s[7] * 64 + lane];
        ax0 += bflo(u0); ay0 += bfhi(u0);
        ax1 += bflo(u1); ay1 += bfhi(u1);
        ax2 += bflo(u2); ay2 += bfhi(u2);
        ax3 += bflo(u3); ay3 += bfhi(u3);
        ax0 += bflo(u4); ay0 += bfhi(u4);
        ax1 += bflo(u5); ay1 += bfhi(u5);
        ax2 += bflo(u6); ay2 += bfhi(u6);
        ax3 += bflo(u7); ay3 += bfhi(u7);
    }
    for (; i < d; ++i) {
        unsigned u = y[(int)row[i] * 64 + lane];
        ax0 += bflo(u); ay0 += bfhi(u);
    }
    float inv = 1.0f / fmaxf((float)d_true, 1.0f);
    float2 z = ((const float2*)Z)[wid * 64 + lane];
    float2 r;
    r.x = (ax0 + ax1 + ax2 + ax3) * inv + z.x;
    r.y = (ay0 + ay1 + ay2 + ay3) * inv + z.y;
    ((float2*)out)[wid * 64 + lane] = r;
}

// ---------------- cooperative mega-kernel: 3 phases, 2 grid syncs ----------
__global__ __launch_bounds__(256, 2) void mega_kernel(
        const float* __restrict__ feat,
        const int* __restrict__ eidx,
        const float* __restrict__ Wl,
        const float* __restrict__ bl,
        const float* __restrict__ Wr,
        bf16_t* __restrict__ feat_bf,
        bf16_t* __restrict__ Bp,
        int* __restrict__ deg,
        unsigned short* __restrict__ bucket,
        bf16_t* __restrict__ Y,
        float* __restrict__ Z,
        float* __restrict__ out) {
    cg::grid_group grid = cg::this_grid();
    const int gid = blockIdx.x * 256 + threadIdx.x;      // 0 .. NB*256-1

    // Phase 0: zero deg + feat cvt + Bp pack
    for (int i = gid; i < (N_NODES * DEG_PAD) / 4; i += NB * 256) {
        int4 zz = {0, 0, 0, 0};
        ((int4*)deg)[i] = zz;
    }
    do_feat_cvt(feat, feat_bf, gid, NB * 256);
    do_bp_pack(Wl, Wr, Bp, gid);
    grid.sync();

    // Phase 1: GEMM blocks || fill blocks (fill is occupancy-insensitive, R10)
    if (blockIdx.x < GEMM_NB) {
        int wv   = blockIdx.x * 4 + (threadIdx.x >> 6);  // 0..1023
        int lane = threadIdx.x & 63;
        for (int wid = wv; wid < N_TILES; wid += GEMM_NB * 4)
            do_gemm_tile(wid, lane, feat_bf, Bp, bl, Y, Z);
    } else {
        int tid = (blockIdx.x - GEMM_NB) * 256 + threadIdx.x;
        for (int e = tid; e < N_EDGES; e += FILL_T) {
            int src = eidx[e];
            int dst = eidx[N_EDGES + e];
            int pos = atomicAdd(&deg[dst * DEG_PAD], 1);
            if (pos < CAP) bucket[dst * CAP + pos] = (unsigned short)src;
        }
    }
    grid.sync();

    // Phase 2: out[i] = mean_{j in N(i)} Y[j] + Z[i]
    int wv   = gid >> 6;                     // 0 .. 2047
    int lane = threadIdx.x & 63;
    for (int wid = wv; wid < N_NODES; wid += (NB * 256) / 64)
        do_gather_node(wid, lane, Y, Z, deg, bucket, out);
}

// ---------------- fallback path (R8-proven 3-kernel pipeline) --------------
__global__ __launch_bounds__(256) void prep_fill_kernel(
        const float* __restrict__ feat, const float* __restrict__ Wl,
        const float* __restrict__ Wr, const int* __restrict__ eidx,
        bf16_t* __restrict__ feat_bf, bf16_t* __restrict__ Bp,
        int* __restrict__ deg, unsigned short* __restrict__ bucket) {
    int t = blockIdx.x * 256 + threadIdx.x;    // 0 .. 639999
    {
        float4 v = ((const float4*)feat)[t];
        ushort4 o = { f2bf(v.x), f2bf(v.y), f2bf(v.z), f2bf(v.w) };
        ((ushort4*)feat_bf)[t] = o;
    }
    int src = eidx[t];
    int dst = eidx[N_EDGES + t];
    int pos = atomicAdd(&deg[dst * DEG_PAD], 1);
    if (pos < CAP) bucket[dst * CAP + pos] = (unsigned short)src;
    do_bp_pack(Wl, Wr, Bp, t);
}
__global__ __launch_bounds__(256) void gemm_kernel(
        const bf16_t* __restrict__ feat_bf, const bf16_t* __restrict__ Bp,
        const float* __restrict__ bl, bf16_t* __restrict__ Y,
        float* __restrict__ Z) {
    int wid = blockIdx.x * 4 + (threadIdx.x >> 6);
    if (wid >= N_TILES) return;
    do_gemm_tile(wid, threadIdx.x & 63, feat_bf, Bp, bl, Y, Z);
}
__global__ __launch_bounds__(256) void gather_final_kernel(
        const bf16_t* __restrict__ Y, const float* __restrict__ Z,
        const int* __restrict__ deg, const unsigned short* __restrict__ bucket,
        float* __restrict__ out) {
    int wid = (blockIdx.x * 256 + threadIdx.x) >> 6;
    if (wid >= N_NODES) return;
    do_gather_node(wid, threadIdx.x & 63, Y, Z, deg, bucket, out);
}

extern "C" void kernel_launch(void* const* d_in, const int* in_sizes, int n_in,
                              void* d_out, int out_size, void* d_ws, size_t ws_size,
                              hipStream_t stream) {
    const float* feat = (const float*)d_in[0];
    const int*   eidx = (const int*)d_in[1];
    const float* Wl   = (const float*)d_in[2];
    const float* bl   = (const float*)d_in[3];
    const float* Wr   = (const float*)d_in[4];
    float* out = (float*)d_out;

    // workspace layout (~25.6 MB; ws is 256 MiB); 16B-aligned sections
    int*            deg     = (int*)d_ws;                                   // 20000*16 int
    unsigned short* bucket  = (unsigned short*)(deg + N_NODES * DEG_PAD);   // 20000*96 u16
    bf16_t*         Bp      = (bf16_t*)(bucket + (size_t)N_NODES * CAP);    // 32768 bf16
    bf16_t*         feat_bf = Bp + 2 * HIDDEN * HIDDEN;                     // 20000*128 bf16
    bf16_t*         Y       = feat_bf + (size_t)N_NODES * HIDDEN;           // 20000*128 bf16
    float*          Z       = (float*)(Y + (size_t)N_NODES * HIDDEN);       // 20000*128 fp32

    void* args[] = { (void*)&feat, (void*)&eidx, (void*)&Wl, (void*)&bl, (void*)&Wr,
                     (void*)&feat_bf, (void*)&Bp, (void*)&deg, (void*)&bucket,
                     (void*)&Y, (void*)&Z, (void*)&out };
    hipError_t err = hipLaunchCooperativeKernel((void*)mega_kernel, dim3(NB),
                                                dim3(256), args, 0, stream);
    if (err != hipSuccess) {
        // deterministic fallback: R8-proven 3-kernel pipeline
        hipMemsetAsync(deg, 0, (size_t)N_NODES * DEG_PAD * sizeof(int), stream);
        prep_fill_kernel<<<N_EDGES / 256, 256, 0, stream>>>(
            feat, Wl, Wr, eidx, feat_bf, Bp, deg, bucket);
        gemm_kernel<<<(N_TILES + 3) / 4, 256, 0, stream>>>(feat_bf, Bp, bl, Y, Z);
        gather_final_kernel<<<(N_NODES * 64) / 256, 256, 0, stream>>>(
            Y, Z, deg, bucket, out);
    }
}

// Round 13
// 139.548 us; speedup vs baseline: 2.2409x; 2.2409x over previous
//
#include <hip/hip_runtime.h>

#define N_NODES 20000
#define N_EDGES 640000
#define HIDDEN  128
#define CAP     96        // max in-degree; Binomial(640K,1/20K) tail @96 ~ e^-45
#define DEG_PAD 16        // one counter per 64B line
#define GEMM_NB 313       // 313*4 = 1252 waves >= 1250 16-row tiles
#define FILL_NB 2500      // 640000 edges, 1/thread (R10: ILP/occupancy don't help)
#define N_TILES (N_NODES / 16)

typedef unsigned short bf16_t;
typedef __attribute__((ext_vector_type(8))) short short8;             // 8 bf16
typedef __attribute__((ext_vector_type(8))) unsigned short ushort8_t; // 8 u16
typedef __attribute__((ext_vector_type(4))) float floatx4;            // MFMA C/D

__device__ __forceinline__ bf16_t f2bf(float f) {
    union { float f; unsigned int i; } v; v.f = f;
    unsigned int x = v.i + 0x7FFFu + ((v.i >> 16) & 1u);   // RNE
    return (bf16_t)(x >> 16);
}
__device__ __forceinline__ float bflo(unsigned u) {
    union { unsigned i; float f; } v; v.i = u << 16; return v.f;
}
__device__ __forceinline__ float bfhi(unsigned u) {
    union { unsigned i; float f; } v; v.i = u & 0xFFFF0000u; return v.f;
}

// --- k1: feat fp32->bf16 + deg zero + Bp weight pack ----------------------
// (memset dispatch folded in: only the 20000 used counter words need zeroing)
__global__ __launch_bounds__(256) void prep_kernel(
        const float* __restrict__ feat,
        const float* __restrict__ Wl,
        const float* __restrict__ Wr,
        bf16_t* __restrict__ feat_bf,
        bf16_t* __restrict__ Bp,
        int* __restrict__ deg) {
    int t = blockIdx.x * 256 + threadIdx.x;    // 0 .. 639999 exactly
    {
        float4 v = ((const float4*)feat)[t];
        ushort4 o = { f2bf(v.x), f2bf(v.y), f2bf(v.z), f2bf(v.w) };
        ((ushort4*)feat_bf)[t] = o;
    }
    if (t < N_NODES) deg[t * DEG_PAD] = 0;
    // Bp t = ((kt*16+nt)*64+lane)*8+j holds B[k][n]; k=kt*32+(lane>>4)*8+j,
    // n=nt*16+(lane&15); n<128 -> W_l (Y half), n>=128 -> W_r (Z half)
    if (t < 2 * HIDDEN * HIDDEN) {
        int j    = t & 7;
        int lane = (t >> 3) & 63;
        int nt   = (t >> 9) & 15;
        int kt   = t >> 13;
        int n = nt * 16 + (lane & 15);
        int k = kt * 32 + (lane >> 4) * 8 + j;
        float w = (n < HIDDEN) ? Wl[n * HIDDEN + k] : Wr[(n - HIDDEN) * HIDDEN + k];
        Bp[t] = f2bf(w);
    }
}

// --- k2: block-split  MFMA GEMM (blocks 0..312)  ||  bucket fill (rest) ----
// R10: fill is memory-side throughput-capped, insensitive to occupancy ->
// sharing the GEMM's ~100-VGPR budget costs fill nothing; GEMM (~13us)
// hides entirely under fill (~40us). [R12: cooperative fusion abandoned]
__global__ __launch_bounds__(256) void fill_gemm_kernel(
        const bf16_t* __restrict__ feat_bf,
        const bf16_t* __restrict__ Bp,
        const float* __restrict__ bl,
        const int* __restrict__ eidx,
        bf16_t* __restrict__ Y,
        float* __restrict__ Z,
        int* __restrict__ deg,
        unsigned short* __restrict__ bucket) {
    if (blockIdx.x < GEMM_NB) {
        // Y = feat@Wl^T (bf16), Z = feat@Wr^T + b (fp32)
        // A-frag: lane holds A[m=lane&15][k=kt*32+(lane>>4)*8+j]; B prepacked;
        // C/D: col=lane&15, row=(lane>>4)*4+r  [m89-verified]
        int wid = blockIdx.x * 4 + (threadIdx.x >> 6);
        if (wid >= N_TILES) return;
        int lane = threadIdx.x & 63;
        int m    = lane & 15;
        int quad = lane >> 4;
        int row0 = wid * 16;

        floatx4 acc[16];
        floatx4 zf = {0.f, 0.f, 0.f, 0.f};
#pragma unroll
        for (int nt = 0; nt < 16; ++nt) acc[nt] = zf;

        const short8* bp = (const short8*)Bp;
#pragma unroll
        for (int kt = 0; kt < 4; ++kt) {
            short8 afrag = *(const short8*)(feat_bf + (size_t)(row0 + m) * HIDDEN
                                            + kt * 32 + quad * 8);
#pragma unroll
            for (int nt = 0; nt < 16; ++nt) {
                short8 bfrag = bp[(kt * 16 + nt) * 64 + lane];
                acc[nt] = __builtin_amdgcn_mfma_f32_16x16x32_bf16(afrag, bfrag, acc[nt], 0, 0, 0);
            }
        }
        int col = lane & 15;
#pragma unroll
        for (int nt = 0; nt < 8; ++nt) {            // Y half (W_l), bf16
#pragma unroll
            for (int r = 0; r < 4; ++r) {
                int row = row0 + quad * 4 + r;
                Y[(size_t)row * HIDDEN + nt * 16 + col] = f2bf(acc[nt][r]);
            }
        }
#pragma unroll
        for (int nt = 8; nt < 16; ++nt) {           // Z half (W_r) + bias, fp32
            float b = bl[(nt - 8) * 16 + col];
#pragma unroll
            for (int r = 0; r < 4; ++r) {
                int row = row0 + quad * 4 + r;
                Z[(size_t)row * HIDDEN + (nt - 8) * 16 + col] = acc[nt][r] + b;
            }
        }
    } else {
        int e = (blockIdx.x - GEMM_NB) * 256 + threadIdx.x;
        if (e >= N_EDGES) return;
        int src = eidx[e];
        int dst = eidx[N_EDGES + e];
        int pos = atomicAdd(&deg[dst * DEG_PAD], 1);
        if (pos < CAP) bucket[dst * CAP + pos] = (unsigned short)src;
    }
}

// --- k3: out[i] = mean_{j in N(i)} Y[j] + Z[i]   (one wave64 per node) -----
// 16 independent Y-row gathers in flight (two ushort8 index vectors).
__global__ __launch_bounds__(256) void gather_final_kernel(
        const bf16_t* __restrict__ Y,
        const float* __restrict__ Z,
        const int* __restrict__ deg,
        const unsigned short* __restrict__ bucket,
        float* __restrict__ out) {
    int wid  = (blockIdx.x * 256 + threadIdx.x) >> 6;
    int lane = threadIdx.x & 63;
    if (wid >= N_NODES) return;
    int d_true = deg[wid * DEG_PAD];
    int d = min(d_true, CAP);
    const unsigned short* row = bucket + (size_t)wid * CAP;   // 192B-aligned
    const unsigned* y = (const unsigned*)Y;                   // packed bf16 pairs
    float ax0=0,ay0=0, ax1=0,ay1=0, ax2=0,ay2=0, ax3=0,ay3=0;
    int i = 0;
    for (; i + 16 <= d; i += 16) {
        ushort8_t s0 = *(const ushort8_t*)(row + i);
        ushort8_t s1 = *(const ushort8_t*)(row + i + 8);
        unsigned u0 = y[(int)s0[0] * 64 + lane];
        unsigned u1 = y[(int)s0[1] * 64 + lane];
        unsigned u2 = y[(int)s0[2] * 64 + lane];
        unsigned u3 = y[(int)s0[3] * 64 + lane];
        unsigned u4 = y[(int)s0[4] * 64 + lane];
        unsigned u5 = y[(int)s0[5] * 64 + lane];
        unsigned u6 = y[(int)s0[6] * 64 + lane];
        unsigned u7 = y[(int)s0[7] * 64 + lane];
        unsigned v0 = y[(int)s1[0] * 64 + lane];
        unsigned v1 = y[(int)s1[1] * 64 + lane];
        unsigned v2 = y[(int)s1[2] * 64 + lane];
        unsigned v3 = y[(int)s1[3] * 64 + lane];
        unsigned v4 = y[(int)s1[4] * 64 + lane];
        unsigned v5 = y[(int)s1[5] * 64 + lane];
        unsigned v6 = y[(int)s1[6] * 64 + lane];
        unsigned v7 = y[(int)s1[7] * 64 + lane];
        ax0 += bflo(u0); ay0 += bfhi(u0);
        ax1 += bflo(u1); ay1 += bfhi(u1);
        ax2 += bflo(u2); ay2 += bfhi(u2);
        ax3 += bflo(u3); ay3 += bfhi(u3);
        ax0 += bflo(u4); ay0 += bfhi(u4);
        ax1 += bflo(u5); ay1 += bfhi(u5);
        ax2 += bflo(u6); ay2 += bfhi(u6);
        ax3 += bflo(u7); ay3 += bfhi(u7);
        ax0 += bflo(v0); ay0 += bfhi(v0);
        ax1 += bflo(v1); ay1 += bfhi(v1);
        ax2 += bflo(v2); ay2 += bfhi(v2);
        ax3 += bflo(v3); ay3 += bfhi(v3);
        ax0 += bflo(v4); ay0 += bfhi(v4);
        ax1 += bflo(v5); ay1 += bfhi(v5);
        ax2 += bflo(v6); ay2 += bfhi(v6);
        ax3 += bflo(v7); ay3 += bfhi(v7);
    }
    for (; i + 8 <= d; i += 8) {
        ushort8_t s = *(const ushort8_t*)(row + i);
        unsigned u0 = y[(int)s[0] * 64 + lane];
        unsigned u1 = y[(int)s[1] * 64 + lane];
        unsigned u2 = y[(int)s[2] * 64 + lane];
        unsigned u3 = y[(int)s[3] * 64 + lane];
        unsigned u4 = y[(int)s[4] * 64 + lane];
        unsigned u5 = y[(int)s[5] * 64 + lane];
        unsigned u6 = y[(int)s[6] * 64 + lane];
        unsigned u7 = y[(int)s[7] * 64 + lane];
        ax0 += bflo(u0); ay0 += bfhi(u0);
        ax1 += bflo(u1); ay1 += bfhi(u1);
        ax2 += bflo(u2); ay2 += bfhi(u2);
        ax3 += bflo(u3); ay3 += bfhi(u3);
        ax0 += bflo(u4); ay0 += bfhi(u4);
        ax1 += bflo(u5); ay1 += bfhi(u5);
        ax2 += bflo(u6); ay2 += bfhi(u6);
        ax3 += bflo(u7); ay3 += bfhi(u7);
    }
    for (; i < d; ++i) {
        unsigned u = y[(int)row[i] * 64 + lane];
        ax0 += bflo(u); ay0 += bfhi(u);
    }
    float inv = 1.0f / fmaxf((float)d_true, 1.0f);
    float2 z = ((const float2*)Z)[wid * 64 + lane];
    float2 r;
    r.x = (ax0 + ax1 + ax2 + ax3) * inv + z.x;
    r.y = (ay0 + ay1 + ay2 + ay3) * inv + z.y;
    ((float2*)out)[wid * 64 + lane] = r;
}

extern "C" void kernel_launch(void* const* d_in, const int* in_sizes, int n_in,
                              void* d_out, int out_size, void* d_ws, size_t ws_size,
                              hipStream_t stream) {
    const float* feat = (const float*)d_in[0];
    const int*   eidx = (const int*)d_in[1];
    const float* Wl   = (const float*)d_in[2];
    const float* bl   = (const float*)d_in[3];
    const float* Wr   = (const float*)d_in[4];
    float* out = (float*)d_out;

    // workspace layout (~25.6 MB; ws is 256 MiB); 16B-aligned sections
    int*            deg     = (int*)d_ws;                                   // 20000*16 int
    unsigned short* bucket  = (unsigned short*)(deg + N_NODES * DEG_PAD);   // 20000*96 u16
    bf16_t*         Bp      = (bf16_t*)(bucket + (size_t)N_NODES * CAP);    // 32768 bf16
    bf16_t*         feat_bf = Bp + 2 * HIDDEN * HIDDEN;                     // 20000*128 bf16
    bf16_t*         Y       = feat_bf + (size_t)N_NODES * HIDDEN;           // 20000*128 bf16
    float*          Z       = (float*)(Y + (size_t)N_NODES * HIDDEN);       // 20000*128 fp32

    prep_kernel<<<2500, 256, 0, stream>>>(feat, Wl, Wr, feat_bf, Bp, deg);
    fill_gemm_kernel<<<GEMM_NB + FILL_NB, 256, 0, stream>>>(
        feat_bf, Bp, bl, eidx, Y, Z, deg, bucket);
    gather_final_kernel<<<(N_NODES * 64) / 256, 256, 0, stream>>>(
        Y, Z, deg, bucket, out);
}